// Round 4
// baseline (1156.236 us; speedup 1.0000x reference)
//
#include <hip/hip_runtime.h>
#include <stdint.h>

#define H 512
#define W 512
#define HW (H * W)
#define NIMG 128
#define AX 26214
#define NB 8192
#define CAND_CAP 7168
#define GCAP 8192

// ws layout
#define WS_SUM 0
#define WS_THR 64
#define WS_B0K1 4096
#define WS_GCNT 8192
#define WS_GHIST 16384
#define WS_GCAND (16384 + 256 * NB * 4)
#define WS_NEED (WS_GCAND + 256 * GCAP * 4)

__device__ __forceinline__ float4 f4zero() { return make_float4(0.f, 0.f, 0.f, 0.f); }

// Find bin b such that suffix_excl(b) < K <= suffix_excl(b) + hist[b].
// Block = 512 threads; hist has NB=8192 bins.
__device__ __forceinline__ void block_select(uint32_t* hist, uint32_t* chunkSuf,
                                             uint32_t* outBin, uint32_t* outRank,
                                             uint32_t K) {
  int tid = threadIdx.x;
  int base = tid * 16;
  uint32_t csum = 0;
#pragma unroll
  for (int k = 0; k < 16; k++) csum += hist[base + k];
  chunkSuf[tid] = csum;
  __syncthreads();
  if (tid < 64) {
    uint32_t cs[8];
    uint32_t g = 0;
#pragma unroll
    for (int m = 0; m < 8; m++) { cs[m] = chunkSuf[tid * 8 + m]; g += cs[m]; }
    uint32_t v = g;
#pragma unroll
    for (int off = 1; off < 64; off <<= 1) {
      uint32_t u = __shfl_down(v, off);
      if (tid + off < 64) v += u;
    }
    uint32_t run = v - g;
    for (int m = 7; m >= 0; m--) {
      chunkSuf[tid * 8 + m] = run;
      run += cs[m];
    }
  }
  __syncthreads();
  uint32_t run = chunkSuf[tid];
  for (int k = 15; k >= 0; k--) {
    uint32_t h = hist[base + k];
    if (run < K && run + h >= K) {
      *outBin = (uint32_t)(base + k);
      *outRank = K - run;
    }
    run += h;
  }
  __syncthreads();
}

// Traverse one 64-row slice of one image (block = 256 thr: 2 row-strips x 128
// col-groups of 4). Ring-4 row pipeline, prefetch distance 3. PASS 0: LDS
// histogram of squared-mag bits>>19. PASS 1: compact matching bin to global.
template <int PASS>
__device__ __forceinline__ void slice_pass(const float* __restrict__ x, int slice,
                                           uint32_t* hist, uint32_t b0,
                                           uint32_t* cnt, uint32_t* cand) {
  int tid = threadIdx.x;
  int wl = tid & 63;
  int lane_c = (tid & 127) << 2;
  int r0 = slice * 64 + (tid >> 7) * 32;
  const bool haveE = lane_c + 4 < W;

  float4 v[4];
  float e[4];
#define LDROW(r, slot)                                              \
  {                                                                 \
    int _r = (r);                                                   \
    if (_r < H) {                                                   \
      v[slot] = *(const float4*)(x + _r * W + lane_c);              \
      e[slot] = (wl == 63 && haveE) ? x[_r * W + lane_c + 4] : 0.f; \
    } else { v[slot] = f4zero(); e[slot] = 0.f; }                   \
  }
  LDROW(r0, 0) LDROW(r0 + 1, 1) LDROW(r0 + 2, 2)
  for (int k0 = 0; k0 < 32; k0 += 4) {
#pragma unroll
    for (int p = 0; p < 4; ++p) {
      int k = k0 + p;
      LDROW(r0 + k + 3, (p + 3) & 3)
      float4 vA = v[p];
      float4 vB = v[(p + 1) & 3];
      float ea = __shfl(vA.x, wl + 1); if (wl == 63) ea = e[p];
      float eb = __shfl(vB.x, wl + 1); if (wl == 63) eb = e[(p + 1) & 3];
      float a[5] = {vA.x, vA.y, vA.z, vA.w, ea};
      float bb[5] = {vB.x, vB.y, vB.z, vB.w, eb};
#pragma unroll
      for (int j = 0; j < 4; j++) {
        float g0 = a[j] - bb[j + 1];
        float g1 = a[j + 1] - bb[j];
        uint32_t bits = __float_as_uint(fmaf(g0, g0, fmaf(g1, g1, 1e-12f)));
        if constexpr (PASS == 0) {
          atomicAdd(&hist[bits >> 19], 1u);
        } else {
          if ((bits >> 19) == b0) {
            uint32_t idx = atomicAdd(cnt, 1u);
            if (idx < GCAP) cand[idx] = bits;
          }
        }
      }
    }
  }
#undef LDROW
}

__global__ __launch_bounds__(256) void zeroKernel(double* __restrict__ sum,
                                                  uint32_t* __restrict__ ghist,
                                                  uint32_t* __restrict__ gcnt,
                                                  int split) {
  size_t g = (size_t)blockIdx.x * 256 + threadIdx.x;
  if (g == 0) *sum = 0.0;
  if (!split) return;
  if (g < 256) gcnt[g] = 0;
  uint4* gh4 = (uint4*)ghist;
  size_t n4 = (size_t)256 * NB / 4;
  for (size_t i = g; i < n4; i += (size_t)gridDim.x * 256)
    gh4[i] = make_uint4(0, 0, 0, 0);
}

__global__ __launch_bounds__(256) void histKernel(const float* __restrict__ target,
                                                  const float* __restrict__ pred,
                                                  uint32_t* __restrict__ ghist) {
  __shared__ uint32_t hist[NB];
  int tid = threadIdx.x;
  for (int i = tid; i < NB; i += 256) hist[i] = 0;
  __syncthreads();
  int b = blockIdx.x;
  int slice = b & 7;
  int imgT = b >> 3;  // [0..127]=target, [128..255]=pred
  const float* __restrict__ x =
      ((imgT >> 7) ? pred : target) + (size_t)(imgT & 127) * HW;
  slice_pass<0>(x, slice, hist, 0, nullptr, nullptr);
  __syncthreads();
  uint32_t* gh = ghist + (size_t)imgT * NB;
  for (int i = tid; i < NB; i += 256) {
    uint32_t h = hist[i];
    if (h) atomicAdd(&gh[i], h);
  }
}

__global__ __launch_bounds__(512) void round1Kernel(const uint32_t* __restrict__ ghist,
                                                    uint2* __restrict__ b0K1) {
  __shared__ uint32_t hist[NB];
  __shared__ uint32_t chunkSuf[512];
  __shared__ uint32_t sBin, sRank;
  int tid = threadIdx.x;
  const uint32_t* gh = ghist + (size_t)blockIdx.x * NB;
  for (int i = tid; i < NB; i += 512) hist[i] = gh[i];
  __syncthreads();
  block_select(hist, chunkSuf, &sBin, &sRank, AX);
  if (tid == 0) b0K1[blockIdx.x] = make_uint2(sBin, sRank);
}

__global__ __launch_bounds__(256) void compactKernel(const float* __restrict__ target,
                                                     const float* __restrict__ pred,
                                                     const uint2* __restrict__ b0K1,
                                                     uint32_t* __restrict__ gcnt,
                                                     uint32_t* __restrict__ gcand) {
  int b = blockIdx.x;
  int slice = b & 7;
  int imgT = b >> 3;
  const float* __restrict__ x =
      ((imgT >> 7) ? pred : target) + (size_t)(imgT & 127) * HW;
  uint32_t b0 = b0K1[imgT].x;
  slice_pass<1>(x, slice, nullptr, b0, &gcnt[imgT], gcand + (size_t)imgT * GCAP);
}

__global__ __launch_bounds__(512) void finalSelKernel(const uint2* __restrict__ b0K1,
                                                      const uint32_t* __restrict__ gcnt,
                                                      const uint32_t* __restrict__ gcand,
                                                      float* __restrict__ thr) {
  __shared__ uint32_t hist[NB];
  __shared__ uint32_t chunkSuf[512];
  __shared__ uint32_t sBin, sRank;
  int tid = threadIdx.x;
  int imgT = blockIdx.x;
  uint32_t b0 = b0K1[imgT].x, K1 = b0K1[imgT].y;
  uint32_t cnt = gcnt[imgT];
  if (cnt > GCAP) cnt = GCAP;
  const uint32_t* cand = gcand + (size_t)imgT * GCAP;
  for (int i = tid; i < NB; i += 512) hist[i] = 0;
  __syncthreads();
  for (uint32_t j = tid; j < cnt; j += 512)
    atomicAdd(&hist[(cand[j] >> 6) & 0x1FFFu], 1u);
  __syncthreads();
  block_select(hist, chunkSuf, &sBin, &sRank, K1);
  uint32_t b1 = sBin, K2 = sRank;
  __syncthreads();
  for (int i = tid; i < NB; i += 512) hist[i] = 0;
  __syncthreads();
  for (uint32_t j = tid; j < cnt; j += 512) {
    uint32_t bits = cand[j];
    if (((bits >> 6) & 0x1FFFu) == b1) atomicAdd(&hist[bits & 63u], 1u);
  }
  __syncthreads();
  block_select(hist, chunkSuf, &sBin, &sRank, K2);
  if (tid == 0) thr[imgT] = __uint_as_float((b0 << 19) | (b1 << 6) | sBin);
}

// ---- Monolithic fallback select (R3 version) if ws is too small ----
template <int PASS>
__device__ __forceinline__ void select_pass(const float* __restrict__ x,
                                            uint32_t* hist, uint32_t* cand,
                                            uint32_t* sCnt, uint32_t b0) {
  int tid = threadIdx.x;
  int wl = tid & 63;
  int lane_c = (tid & 127) << 2;
  int r0 = (tid >> 7) * 128;
  const bool haveE = lane_c + 4 < W;
  float4 vA, vB, vC;
  float eA = 0.f, eB = 0.f, eC = 0.f;
#define LDROW(r, v, e)                                          \
  {                                                             \
    if ((r) < H) {                                              \
      v = *(const float4*)(x + (r) * W + lane_c);               \
      if (wl == 63) e = haveE ? x[(r) * W + lane_c + 4] : 0.f;  \
    } else { v = f4zero(); e = 0.f; }                           \
  }
  LDROW(r0, vA, eA)
  LDROW(r0 + 1, vB, eB)
  for (int it = 0; it < 128; ++it) {
    int r = r0 + it;
    if (it < 127) { LDROW(r + 2, vC, eC) } else { vC = f4zero(); eC = 0.f; }
    float ea = __shfl(vA.x, wl + 1); if (wl == 63) ea = eA;
    float eb = __shfl(vB.x, wl + 1); if (wl == 63) eb = eB;
    float a[5] = {vA.x, vA.y, vA.z, vA.w, ea};
    float bb[5] = {vB.x, vB.y, vB.z, vB.w, eb};
#pragma unroll
    for (int j = 0; j < 4; j++) {
      float g0 = a[j] - bb[j + 1];
      float g1 = a[j + 1] - bb[j];
      float msq = fmaf(g0, g0, fmaf(g1, g1, 1e-12f));
      uint32_t bits = __float_as_uint(msq);
      if constexpr (PASS == 0) {
        atomicAdd(&hist[bits >> 19], 1u);
      } else {
        if ((bits >> 19) == b0) {
          uint32_t idx = atomicAdd(sCnt, 1u);
          if (idx < CAND_CAP) cand[idx] = bits;
        }
      }
    }
    vA = vB; eA = eB; vB = vC; eB = eC;
  }
#undef LDROW
}

__global__ __launch_bounds__(512) void selectKernel(const float* __restrict__ target,
                                                    const float* __restrict__ pred,
                                                    float* __restrict__ thr) {
  __shared__ uint32_t hist[NB];
  __shared__ uint32_t cand[CAND_CAP];
  __shared__ uint32_t chunkSuf[512];
  __shared__ uint32_t sBin, sRank, sCnt;
  int tid = threadIdx.x;
  int b = blockIdx.x;
  const float* __restrict__ x = ((b >> 7) ? pred : target) + (size_t)(b & 127) * HW;
  for (int i = tid; i < NB; i += 512) hist[i] = 0;
  if (tid == 0) { sBin = 0; sRank = 1; sCnt = 0; }
  __syncthreads();
  select_pass<0>(x, hist, cand, &sCnt, 0);
  __syncthreads();
  block_select(hist, chunkSuf, &sBin, &sRank, AX);
  uint32_t b0 = sBin;
  uint32_t K1 = sRank;
  __syncthreads();
  select_pass<1>(x, hist, cand, &sCnt, b0);
  __syncthreads();
  uint32_t cnt = sCnt;
  if (cnt > CAND_CAP) cnt = CAND_CAP;
  for (int i = tid; i < NB; i += 512) hist[i] = 0;
  __syncthreads();
  for (uint32_t j = tid; j < cnt; j += 512)
    atomicAdd(&hist[(cand[j] >> 6) & 0x1FFFu], 1u);
  __syncthreads();
  block_select(hist, chunkSuf, &sBin, &sRank, K1);
  uint32_t b1 = sBin;
  uint32_t K2 = sRank;
  __syncthreads();
  for (int i = tid; i < NB; i += 512) hist[i] = 0;
  __syncthreads();
  for (uint32_t j = tid; j < cnt; j += 512) {
    uint32_t bits = cand[j];
    if (((bits >> 6) & 0x1FFFu) == b1) atomicAdd(&hist[bits & 63u], 1u);
  }
  __syncthreads();
  block_select(hist, chunkSuf, &sBin, &sRank, K2);
  if (tid == 0) thr[b] = __uint_as_float((b0 << 19) | (b1 << 6) | sBin);
}

// Per-position sequential carry over images. 512 blocks (1 row each, XCD-banded),
// 256 thr, float2/thread, ring-4 image pipeline with prefetch distance 3.
__global__ __launch_bounds__(256) void scanKernel(const float* __restrict__ target,
                                                  const float* __restrict__ pred,
                                                  const float* __restrict__ thr,
                                                  double* __restrict__ sum) {
  __shared__ float sT[NIMG], sP[NIMG];
  int tid = threadIdx.x;
  if (tid < NIMG) { sT[tid] = thr[tid]; sP[tid] = thr[NIMG + tid]; }
  __syncthreads();
  int b = blockIdx.x;
  int r = ((b & 7) << 6) | (b >> 3);  // XCD-banded rows
  int wl = tid & 63;
  int c = tid << 1;
  const bool haveE = (wl == 63) && (c + 2 < W);
  const bool haveB = r + 1 < H;
  size_t offA = (size_t)r * W + c;
  size_t offB = offA + W;

  float2 tA[4], tB[4], pA[4], pB[4];
  float eTa[4], eTb[4], ePa[4], ePb[4];
#define LOADI(i, buf)                                                       \
  {                                                                         \
    const float* xt = target + (size_t)(i) * HW;                            \
    const float* xp = pred + (size_t)(i) * HW;                              \
    tA[buf] = *(const float2*)(xt + offA);                                  \
    pA[buf] = *(const float2*)(xp + offA);                                  \
    tB[buf] = haveB ? *(const float2*)(xt + offB) : make_float2(0.f, 0.f);  \
    pB[buf] = haveB ? *(const float2*)(xp + offB) : make_float2(0.f, 0.f);  \
    eTa[buf] = haveE ? xt[offA + 2] : 0.f;                                  \
    ePa[buf] = haveE ? xp[offA + 2] : 0.f;                                  \
    eTb[buf] = (haveE && haveB) ? xt[offB + 2] : 0.f;                       \
    ePb[buf] = (haveE && haveB) ? xp[offB + 2] : 0.f;                       \
  }
#define COMPUTE(buf, i)                                                     \
  {                                                                         \
    float tsT = sT[i], tsP = sP[i];                                         \
    float ea = __shfl(tA[buf].x, wl + 1); if (wl == 63) ea = eTa[buf];      \
    float eb = __shfl(tB[buf].x, wl + 1); if (wl == 63) eb = eTb[buf];      \
    float fa = __shfl(pA[buf].x, wl + 1); if (wl == 63) fa = ePa[buf];      \
    float fb = __shfl(pB[buf].x, wl + 1); if (wl == 63) fb = ePb[buf];      \
    float A[3] = {tA[buf].x, tA[buf].y, ea};                                \
    float Bv[3] = {tB[buf].x, tB[buf].y, eb};                               \
    float Pa[3] = {pA[buf].x, pA[buf].y, fa};                               \
    float Pb[3] = {pB[buf].x, pB[buf].y, fb};                               \
    _Pragma("unroll") for (int j = 0; j < 2; j++) {                         \
      float g0 = A[j] - Bv[j + 1];                                          \
      float g1 = A[j + 1] - Bv[j];                                          \
      float msq = fmaf(g0, g0, fmaf(g1, g1, 1e-12f));                       \
      if (msq >= tsT) etf[j] = sqrtf(msq);                                  \
      g0 = Pa[j] - Pb[j + 1];                                               \
      g1 = Pa[j + 1] - Pb[j];                                               \
      float msp = fmaf(g0, g0, fmaf(g1, g1, 1e-12f));                       \
      if (msp >= tsP) epf[j] = sqrtf(msp);                                  \
      acc += fabsf((etf[j] - epf[j]) / (etf[j] + epf[j] + 1e-5f));          \
    }                                                                       \
  }

  float etf[2] = {0.f, 0.f}, epf[2] = {0.f, 0.f};
  float acc = 0.f;
  LOADI(0, 0) LOADI(1, 1) LOADI(2, 2)
  for (int i = 0; i < NIMG; i += 4) {
    if (i + 3 < NIMG) LOADI(i + 3, 3)
    COMPUTE(0, i)
    if (i + 4 < NIMG) LOADI(i + 4, 0)
    COMPUTE(1, i + 1)
    if (i + 5 < NIMG) LOADI(i + 5, 1)
    COMPUTE(2, i + 2)
    if (i + 6 < NIMG) LOADI(i + 6, 2)
    COMPUTE(3, i + 3)
  }
#undef LOADI
#undef COMPUTE

  for (int off = 32; off; off >>= 1) acc += __shfl_down(acc, off);
  __shared__ float ws4[4];
  if ((tid & 63) == 0) ws4[tid >> 6] = acc;
  __syncthreads();
  if (tid == 0) {
    double s = (double)ws4[0] + (double)ws4[1] + (double)ws4[2] + (double)ws4[3];
    atomicAdd(sum, s);
  }
}

__global__ void finalKernel(const double* __restrict__ sum,
                            const float* __restrict__ alpha,
                            float* __restrict__ out) {
  out[0] = (float)((double)alpha[0] * (sum[0] / (double)((double)NIMG * (double)HW)));
}

extern "C" void kernel_launch(void* const* d_in, const int* in_sizes, int n_in,
                              void* d_out, int out_size, void* d_ws, size_t ws_size,
                              hipStream_t stream) {
  const float* pred = (const float*)d_in[0];    // predictions [16,8,512,512]
  const float* target = (const float*)d_in[1];  // target      [16,8,512,512]
  const float* alpha = (const float*)d_in[2];   // scalar
  // d_in[3] = Roberts kernels (fixed values, hardcoded)

  char* ws = (char*)d_ws;
  double* d_sum = (double*)(ws + WS_SUM);
  float* d_thr = (float*)(ws + WS_THR);
  uint2* d_b0K1 = (uint2*)(ws + WS_B0K1);
  uint32_t* d_gcnt = (uint32_t*)(ws + WS_GCNT);
  uint32_t* d_ghist = (uint32_t*)(ws + WS_GHIST);
  uint32_t* d_gcand = (uint32_t*)(ws + WS_GCAND);

  const int split = (ws_size >= (size_t)WS_NEED) ? 1 : 0;  // ws_size is call-invariant

  zeroKernel<<<2048, 256, 0, stream>>>(d_sum, d_ghist, d_gcnt, split);
  if (split) {
    histKernel<<<2048, 256, 0, stream>>>(target, pred, d_ghist);
    round1Kernel<<<256, 512, 0, stream>>>(d_ghist, d_b0K1);
    compactKernel<<<2048, 256, 0, stream>>>(target, pred, d_b0K1, d_gcnt, d_gcand);
    finalSelKernel<<<256, 512, 0, stream>>>(d_b0K1, d_gcnt, d_gcand, d_thr);
  } else {
    selectKernel<<<256, 512, 0, stream>>>(target, pred, d_thr);
  }
  scanKernel<<<512, 256, 0, stream>>>(target, pred, d_thr, d_sum);
  finalKernel<<<1, 1, 0, stream>>>(d_sum, alpha, (float*)d_out);
}

// Round 5
// 536.610 us; speedup vs baseline: 2.1547x; 2.1547x over previous
//
#include <hip/hip_runtime.h>
#include <stdint.h>

#define H 512
#define W 512
#define HW (H * W)
#define NIMG 128
#define AX 26214
#define NB 8192
#define CAND_CAP 6656
#define BS 1024

__device__ __forceinline__ float4 f4zero() { return make_float4(0.f, 0.f, 0.f, 0.f); }

// Find bin b such that suffix_excl(b) < K <= suffix_excl(b) + hist[b].
// Block = 1024 threads; hist has NB=8192 bins (8 bins/thread).
__device__ __forceinline__ void block_select(uint32_t* hist, uint32_t* chunkSuf,
                                             uint32_t* outBin, uint32_t* outRank,
                                             uint32_t K) {
  int tid = threadIdx.x;
  int base = tid * 8;
  uint32_t csum = 0;
#pragma unroll
  for (int k = 0; k < 8; k++) csum += hist[base + k];
  chunkSuf[tid] = csum;
  __syncthreads();
  if (tid < 64) {
    uint32_t cs[16];
    uint32_t g = 0;
#pragma unroll
    for (int m = 0; m < 16; m++) { cs[m] = chunkSuf[tid * 16 + m]; g += cs[m]; }
    uint32_t v = g;  // inclusive suffix across 64 lanes
#pragma unroll
    for (int off = 1; off < 64; off <<= 1) {
      uint32_t u = __shfl_down(v, off);
      if (tid + off < 64) v += u;
    }
    uint32_t run = v - g;  // sum over lanes > tid
    for (int m = 15; m >= 0; m--) {
      chunkSuf[tid * 16 + m] = run;  // suffix-exclusive per chunk
      run += cs[m];
    }
  }
  __syncthreads();
  uint32_t run = chunkSuf[tid];
  for (int k = 7; k >= 0; k--) {
    uint32_t h = hist[base + k];
    if (run < K && run + h >= K) {
      *outBin = (uint32_t)(base + k);
      *outRank = K - run;
    }
    run += h;
  }
  __syncthreads();
}

// Pass over one image: 1024 thr = 128 col-groups (float4) x 8 row-strips of 64
// rows. Ring-4 row pipeline, prefetch distance 3. PASS 0: LDS histogram of
// squared-mag bits>>19. PASS 1: compact matching bin into LDS.
template <int PASS>
__device__ __forceinline__ void select_pass(const float* __restrict__ x,
                                            uint32_t* hist, uint32_t* cand,
                                            uint32_t* sCnt, uint32_t b0) {
  int tid = threadIdx.x;
  int wl = tid & 63;
  int lane_c = (tid & 127) << 2;
  int r0 = (tid >> 7) * 64;
  const bool haveE = lane_c + 4 < W;

  float4 v[4];
  float e[4];
#define LDROW(r, slot)                                              \
  {                                                                 \
    int _r = (r);                                                   \
    if (_r < H) {                                                   \
      v[slot] = *(const float4*)(x + _r * W + lane_c);              \
      e[slot] = (wl == 63 && haveE) ? x[_r * W + lane_c + 4] : 0.f; \
    } else { v[slot] = f4zero(); e[slot] = 0.f; }                   \
  }
  LDROW(r0, 0) LDROW(r0 + 1, 1) LDROW(r0 + 2, 2)
  for (int k0 = 0; k0 < 64; k0 += 4) {
#pragma unroll
    for (int p = 0; p < 4; ++p) {
      int k = k0 + p;
      LDROW(r0 + k + 3, (p + 3) & 3)
      float4 vA = v[p];
      float4 vB = v[(p + 1) & 3];
      float ea = __shfl(vA.x, wl + 1); if (wl == 63) ea = e[p];
      float eb = __shfl(vB.x, wl + 1); if (wl == 63) eb = e[(p + 1) & 3];
      float a[5] = {vA.x, vA.y, vA.z, vA.w, ea};
      float bb[5] = {vB.x, vB.y, vB.z, vB.w, eb};
#pragma unroll
      for (int j = 0; j < 4; j++) {
        float g0 = a[j] - bb[j + 1];
        float g1 = a[j + 1] - bb[j];
        uint32_t bits = __float_as_uint(fmaf(g0, g0, fmaf(g1, g1, 1e-12f)));
        if constexpr (PASS == 0) {
          atomicAdd(&hist[bits >> 19], 1u);
        } else {
          if ((bits >> 19) == b0) {
            uint32_t idx = atomicAdd(sCnt, 1u);
            if (idx < CAND_CAP) cand[idx] = bits;
          }
        }
      }
    }
  }
#undef LDROW
}

// One block per (tensor, image): exact rank-AX threshold (squared domain,
// sqrt-free) via radix select on float bits. 1024 thr -> 16 waves/CU.
__global__ __launch_bounds__(BS) void selectKernel(const float* __restrict__ target,
                                                   const float* __restrict__ pred,
                                                   float* __restrict__ thr) {
  __shared__ uint32_t hist[NB];        // 32 KB
  __shared__ uint32_t cand[CAND_CAP];  // 26 KB
  __shared__ uint32_t chunkSuf[BS];    // 4 KB
  __shared__ uint32_t sBin, sRank, sCnt;
  int tid = threadIdx.x;
  int b = blockIdx.x;
  const float* __restrict__ x = ((b >> 7) ? pred : target) + (size_t)(b & 127) * HW;

  for (int i = tid; i < NB; i += BS) hist[i] = 0;
  if (tid == 0) { sBin = 0; sRank = 1; sCnt = 0; }
  __syncthreads();

  select_pass<0>(x, hist, cand, &sCnt, 0);
  __syncthreads();
  block_select(hist, chunkSuf, &sBin, &sRank, AX);
  uint32_t b0 = sBin;
  uint32_t K1 = sRank;
  __syncthreads();

  select_pass<1>(x, hist, cand, &sCnt, b0);
  __syncthreads();
  uint32_t cnt = sCnt;
  if (cnt > CAND_CAP) cnt = CAND_CAP;  // expected ~3K; cap far in the tail

  // Mini-round 1: next 13 bits, in-LDS
  for (int i = tid; i < NB; i += BS) hist[i] = 0;
  __syncthreads();
  for (uint32_t j = tid; j < cnt; j += BS)
    atomicAdd(&hist[(cand[j] >> 6) & 0x1FFFu], 1u);
  __syncthreads();
  block_select(hist, chunkSuf, &sBin, &sRank, K1);
  uint32_t b1 = sBin;
  uint32_t K2 = sRank;
  __syncthreads();

  // Mini-round 2: last 6 bits
  for (int i = tid; i < NB; i += BS) hist[i] = 0;
  __syncthreads();
  for (uint32_t j = tid; j < cnt; j += BS) {
    uint32_t bits = cand[j];
    if (((bits >> 6) & 0x1FFFu) == b1) atomicAdd(&hist[bits & 63u], 1u);
  }
  __syncthreads();
  block_select(hist, chunkSuf, &sBin, &sRank, K2);
  if (tid == 0) thr[b] = __uint_as_float((b0 << 19) | (b1 << 6) | sBin);
}

// Per-position sequential carry over images. Thread = 1 col x 2 rows (halo row
// shared -> 1.5x traffic). 512 blocks (2 col-halves x 256 row-pairs,
// XCD-banded), 256 thr, ring-4 image pipeline (3 images in flight).
__global__ __launch_bounds__(256) void scanKernel(const float* __restrict__ target,
                                                  const float* __restrict__ pred,
                                                  const float* __restrict__ thr,
                                                  double* __restrict__ sum) {
  __shared__ float sT[NIMG], sP[NIMG];
  int tid = threadIdx.x;
  if (tid < NIMG) { sT[tid] = thr[tid]; sP[tid] = thr[NIMG + tid]; }
  __syncthreads();
  int by = blockIdx.y;
  int rp = ((by & 7) << 5) | (by >> 3);  // XCD-banded row pairs (64-row bands)
  int r = rp * 2;
  int c = blockIdx.x * 256 + tid;
  int wl = tid & 63;
  const bool okR2 = (r + 2 < H);
  const bool eLane = (wl == 63) && (c + 1 < W);
  size_t off = (size_t)r * W + c;

  // ring buffers: tv/pv = col c rows r..r+2; te/pe = col c+1 (lane 63 only)
  float tv[4][3], pv[4][3], te[4][3], pe[4][3];

#define LOADI(i, buf)                                                    \
  {                                                                      \
    const float* xt = target + (size_t)(i) * HW + off;                   \
    const float* xp = pred + (size_t)(i) * HW + off;                     \
    tv[buf][0] = xt[0];                                                  \
    tv[buf][1] = xt[W];                                                  \
    tv[buf][2] = okR2 ? xt[2 * W] : 0.f;                                 \
    pv[buf][0] = xp[0];                                                  \
    pv[buf][1] = xp[W];                                                  \
    pv[buf][2] = okR2 ? xp[2 * W] : 0.f;                                 \
    te[buf][0] = te[buf][1] = te[buf][2] = 0.f;                          \
    pe[buf][0] = pe[buf][1] = pe[buf][2] = 0.f;                          \
    if (eLane) {                                                         \
      te[buf][0] = xt[1];                                                \
      te[buf][1] = xt[W + 1];                                            \
      te[buf][2] = okR2 ? xt[2 * W + 1] : 0.f;                           \
      pe[buf][0] = xp[1];                                                \
      pe[buf][1] = xp[W + 1];                                            \
      pe[buf][2] = okR2 ? xp[2 * W + 1] : 0.f;                           \
    }                                                                    \
  }

#define COMPUTE(buf, i)                                                  \
  {                                                                      \
    float tsT = sT[i], tsP = sP[i];                                      \
    float tn[3], pn[3];                                                  \
    _Pragma("unroll") for (int k = 0; k < 3; k++) {                      \
      tn[k] = __shfl(tv[buf][k], wl + 1);                                \
      if (wl == 63) tn[k] = te[buf][k];                                  \
      pn[k] = __shfl(pv[buf][k], wl + 1);                                \
      if (wl == 63) pn[k] = pe[buf][k];                                  \
    }                                                                    \
    _Pragma("unroll") for (int j = 0; j < 2; j++) {                      \
      float g0 = tv[buf][j] - tn[j + 1];                                 \
      float g1 = tn[j] - tv[buf][j + 1];                                 \
      float msq = fmaf(g0, g0, fmaf(g1, g1, 1e-12f));                    \
      if (msq >= tsT) etf[j] = sqrtf(msq);                               \
      g0 = pv[buf][j] - pn[j + 1];                                       \
      g1 = pn[j] - pv[buf][j + 1];                                       \
      float msp = fmaf(g0, g0, fmaf(g1, g1, 1e-12f));                    \
      if (msp >= tsP) epf[j] = sqrtf(msp);                               \
      acc += fabsf((etf[j] - epf[j]) / (etf[j] + epf[j] + 1e-5f));       \
    }                                                                    \
  }

  float etf[2] = {0.f, 0.f}, epf[2] = {0.f, 0.f};
  float acc = 0.f;
  LOADI(0, 0) LOADI(1, 1) LOADI(2, 2)
  for (int i = 0; i < NIMG; i += 4) {
    if (i + 3 < NIMG) LOADI(i + 3, 3)
    COMPUTE(0, i)
    if (i + 4 < NIMG) LOADI(i + 4, 0)
    COMPUTE(1, i + 1)
    if (i + 5 < NIMG) LOADI(i + 5, 1)
    COMPUTE(2, i + 2)
    if (i + 6 < NIMG) LOADI(i + 6, 2)
    COMPUTE(3, i + 3)
  }
#undef LOADI
#undef COMPUTE

  for (int off2 = 32; off2; off2 >>= 1) acc += __shfl_down(acc, off2);
  __shared__ float ws4[4];
  if ((tid & 63) == 0) ws4[tid >> 6] = acc;
  __syncthreads();
  if (tid == 0) {
    double s = (double)ws4[0] + (double)ws4[1] + (double)ws4[2] + (double)ws4[3];
    atomicAdd(sum, s);
  }
}

__global__ void initKernel(double* __restrict__ sum) { *sum = 0.0; }

__global__ void finalKernel(const double* __restrict__ sum,
                            const float* __restrict__ alpha,
                            float* __restrict__ out) {
  out[0] = (float)((double)alpha[0] * (sum[0] / (double)((double)NIMG * (double)HW)));
}

extern "C" void kernel_launch(void* const* d_in, const int* in_sizes, int n_in,
                              void* d_out, int out_size, void* d_ws, size_t ws_size,
                              hipStream_t stream) {
  const float* pred = (const float*)d_in[0];    // predictions [16,8,512,512]
  const float* target = (const float*)d_in[1];  // target      [16,8,512,512]
  const float* alpha = (const float*)d_in[2];   // scalar
  // d_in[3] = Roberts kernels (fixed values, hardcoded)

  double* d_sum = (double*)d_ws;
  float* d_thr = (float*)((char*)d_ws + 64);  // 256 floats (squared-threshold bits)

  initKernel<<<1, 1, 0, stream>>>(d_sum);
  selectKernel<<<256, BS, 0, stream>>>(target, pred, d_thr);
  scanKernel<<<dim3(2, 256), 256, 0, stream>>>(target, pred, d_thr, d_sum);
  finalKernel<<<1, 1, 0, stream>>>(d_sum, alpha, (float*)d_out);
}